// Round 1
// baseline (54.949 us; speedup 1.0000x reference)
//
#include <hip/hip_runtime.h>

// NeighborsConvolution: out[z,a,i] = sum_{b,x,j} [|r_b-r_a|<0.5] * (r_b-r_a)_x * W[x,i,j] * feat[z,b,j]
// B=8, N=1024, CIN=COUT=64.
// Strategy: one wave per (z,a). Ballot-based neighbor scan (16 steps of 64
// candidates), shfl-broadcast diff, coalesced feature loads, f32 accumulate.
// Epilogue contracts tmp[3][64] with W[3,64,64] per point.

#define BATCHSZ 8
#define NPTS 1024
#define CIN 64
#define COUT 64

__global__ __launch_bounds__(64) void neigh_conv_kernel(
    const float* __restrict__ feat,   // [B,N,CIN]
    const float* __restrict__ geom,   // [B,N,3]
    const float* __restrict__ W,      // [3,COUT,CIN]
    float* __restrict__ out)          // [B,N,COUT]
{
    const int a    = blockIdx.x & (NPTS - 1);
    const int z    = blockIdx.x >> 10;          // NPTS == 1024
    const int lane = threadIdx.x;               // 0..63

    __shared__ float tmp[3 * CIN];

    const float* gz = geom + (size_t)z * NPTS * 3;
    const float gax = gz[a * 3 + 0];
    const float gay = gz[a * 3 + 1];
    const float gaz = gz[a * 3 + 2];

    const float* fz = feat + (size_t)z * NPTS * CIN;

    float acc0 = 0.f, acc1 = 0.f, acc2 = 0.f;

    for (int bb = 0; bb < NPTS; bb += 64) {
        const int b = bb + lane;
        const float gbx = gz[b * 3 + 0];
        const float gby = gz[b * 3 + 1];
        const float gbz = gz[b * 3 + 2];
        float dx, dy, dz, d2;
        {
            // Match numpy bit-exact near the radius boundary: no fma
            // contraction, left-assoc add order. norm<0.5 <=> d2<0.25 exactly.
            #pragma clang fp contract(off)
            dx = gbx - gax;
            dy = gby - gay;
            dz = gbz - gaz;
            d2 = dx * dx + dy * dy + dz * dz;
        }
        unsigned long long m = __ballot(d2 < 0.25f);
        // m is wave-uniform; loop is non-divergent. ~5 neighbors avg total.
        while (m) {
            const int src = __ffsll((unsigned long long)m) - 1;
            m &= (m - 1);
            const float ddx = __shfl(dx, src);
            const float ddy = __shfl(dy, src);
            const float ddz = __shfl(dz, src);
            const float f = fz[(size_t)(bb + src) * CIN + lane];  // coalesced 256B
            acc0 = fmaf(ddx, f, acc0);
            acc1 = fmaf(ddy, f, acc1);
            acc2 = fmaf(ddz, f, acc2);
        }
    }

    // tmp[x][j] distributed with j = lane -> stage to LDS for the contraction.
    tmp[0 * CIN + lane] = acc0;
    tmp[1 * CIN + lane] = acc1;
    tmp[2 * CIN + lane] = acc2;
    __syncthreads();

    // out[i=lane] = sum_x sum_j tmp[x][j] * W[x][i][j]
    float o = 0.f;
    const float4* t4 = (const float4*)tmp;
    #pragma unroll
    for (int x = 0; x < 3; ++x) {
        const float4* w4 = (const float4*)(W + (size_t)(x * COUT + lane) * CIN);
        #pragma unroll
        for (int j4 = 0; j4 < CIN / 4; ++j4) {
            const float4 w = w4[j4];
            const float4 t = t4[x * (CIN / 4) + j4];  // uniform addr -> LDS broadcast
            o = fmaf(w.x, t.x, o);
            o = fmaf(w.y, t.y, o);
            o = fmaf(w.z, t.z, o);
            o = fmaf(w.w, t.w, o);
        }
    }
    out[((size_t)z * NPTS + a) * COUT + lane] = o;
}

extern "C" void kernel_launch(void* const* d_in, const int* in_sizes, int n_in,
                              void* d_out, int out_size, void* d_ws, size_t ws_size,
                              hipStream_t stream) {
    const float* feat = (const float*)d_in[0];  // [8,1024,64]
    const float* geom = (const float*)d_in[1];  // [8,1024,3]
    const float* W    = (const float*)d_in[2];  // [3,64,64]
    float* out        = (float*)d_out;          // [8,1024,64]

    const int nblocks = BATCHSZ * NPTS;         // 8192 waves, 1 per point
    neigh_conv_kernel<<<nblocks, 64, 0, stream>>>(feat, geom, W, out);
}

// Round 2
// 29.132 us; speedup vs baseline: 1.8862x; 1.8862x over previous
//
#include <hip/hip_runtime.h>

// NeighborsConvolution: out[z,a,i] = sum_{b,x,j} [|r_b-r_a|<0.5] * (r_b-r_a)_x * W[x,i,j] * feat[z,b,j]
// B=8, N=1024, CIN=COUT=64.
//
// R2 changes vs R1 (latency/transaction-bound, VALUBusy 9.7%):
//  - Pre-transpose W -> Wt[(xj/4)][i][xj%4] in d_ws so the epilogue W read is
//    fully coalesced (1KB/instr) instead of 64-line strided (8x fewer txns).
//  - Stage per-batch geometry (12KB) in LDS once per block.
//  - 4 waves/block to lift the 16-workgroup/CU occupancy cap.

#define BATCHSZ 8
#define NPTS 1024
#define CIN 64
#define COUT 64
#define NXJ (3 * CIN)   // 192
#define WPB 4           // waves (= points) per block

__global__ __launch_bounds__(256) void transpose_W_kernel(
    const float* __restrict__ W,   // [3][COUT][CIN]
    float* __restrict__ Wt)        // [NXJ/4][COUT][4]
{
    const int t = blockIdx.x * 256 + threadIdx.x;
    if (t >= 3 * COUT * CIN) return;
    const int x = t >> 12;         // / (COUT*CIN)
    const int i = (t >> 6) & 63;
    const int j = t & 63;
    const int xj = x * CIN + j;
    Wt[((xj >> 2) * COUT + i) * 4 + (xj & 3)] = W[t];
}

template <bool USE_WT>
__global__ __launch_bounds__(WPB * 64, 8) void neigh_conv_kernel(
    const float* __restrict__ feat,  // [B,N,CIN]
    const float* __restrict__ geom,  // [B,N,3]
    const float* __restrict__ Wany,  // USE_WT ? Wt : W
    float* __restrict__ out)         // [B,N,COUT]
{
    const int lane = threadIdx.x & 63;
    const int wv   = threadIdx.x >> 6;
    const int p    = blockIdx.x * WPB + wv;   // global point index
    const int a    = p & (NPTS - 1);
    const int z    = p >> 10;                 // all WPB waves share z (4 | 1024)

    __shared__ __align__(16) float geo[NPTS * 3];   // 12 KB, block-shared (same z)
    __shared__ __align__(16) float tmp[WPB][NXJ];   // 3 KB

    // Cooperative coalesced stage of this batch's geometry.
    {
        const float4* src = (const float4*)(geom + (size_t)z * NPTS * 3);
        float4* dst = (float4*)geo;
        #pragma unroll
        for (int k = threadIdx.x; k < NPTS * 3 / 4; k += WPB * 64)
            dst[k] = src[k];
    }
    __syncthreads();

    const float gax = geo[a * 3 + 0];
    const float gay = geo[a * 3 + 1];
    const float gaz = geo[a * 3 + 2];
    const float* fz = feat + (size_t)z * NPTS * CIN;

    float acc0 = 0.f, acc1 = 0.f, acc2 = 0.f;

    for (int bb = 0; bb < NPTS; bb += 64) {
        const int b = bb + lane;
        float dx, dy, dz, d2;
        {
            // Bit-exact vs numpy near the radius boundary: no fma contraction,
            // left-assoc adds. norm<0.5 <=> d2<0.25 exactly.
            #pragma clang fp contract(off)
            dx = geo[b * 3 + 0] - gax;
            dy = geo[b * 3 + 1] - gay;
            dz = geo[b * 3 + 2] - gaz;
            d2 = dx * dx + dy * dy + dz * dz;
        }
        unsigned long long m = __ballot(d2 < 0.25f);
        // m is wave-uniform; ~5 neighbors total expected across all 16 iters.
        while (m) {
            const int src = __ffsll((unsigned long long)m) - 1;
            m &= (m - 1);
            const float ddx = __shfl(dx, src);
            const float ddy = __shfl(dy, src);
            const float ddz = __shfl(dz, src);
            const float f = fz[(size_t)(bb + src) * CIN + lane];  // coalesced 256B
            acc0 = fmaf(ddx, f, acc0);
            acc1 = fmaf(ddy, f, acc1);
            acc2 = fmaf(ddz, f, acc2);
        }
    }

    tmp[wv][0 * CIN + lane] = acc0;
    tmp[wv][1 * CIN + lane] = acc1;
    tmp[wv][2 * CIN + lane] = acc2;
    __syncthreads();

    float o = 0.f;
    if (USE_WT) {
        // out[i=lane] = sum_g sum_e tmp[4g+e] * Wt[g][i][e]
        const float4* t4 = (const float4*)tmp[wv];       // uniform -> LDS broadcast
        const float4* w4 = (const float4*)Wany;          // lane-coalesced 1KB/instr
        #pragma unroll 4
        for (int g = 0; g < NXJ / 4; ++g) {
            const float4 t = t4[g];
            const float4 w = w4[g * COUT + lane];
            o = fmaf(t.x, w.x, o);
            o = fmaf(t.y, w.y, o);
            o = fmaf(t.z, w.z, o);
            o = fmaf(t.w, w.w, o);
        }
    } else {
        // Fallback (ws too small): original strided-W epilogue.
        const float4* t4 = (const float4*)tmp[wv];
        #pragma unroll
        for (int x = 0; x < 3; ++x) {
            const float4* w4 = (const float4*)(Wany + (size_t)(x * COUT + lane) * CIN);
            #pragma unroll
            for (int j4 = 0; j4 < CIN / 4; ++j4) {
                const float4 w = w4[j4];
                const float4 t = t4[x * (CIN / 4) + j4];
                o = fmaf(w.x, t.x, o);
                o = fmaf(w.y, t.y, o);
                o = fmaf(w.z, t.z, o);
                o = fmaf(w.w, t.w, o);
            }
        }
    }
    out[(size_t)p * COUT + lane] = o;
}

extern "C" void kernel_launch(void* const* d_in, const int* in_sizes, int n_in,
                              void* d_out, int out_size, void* d_ws, size_t ws_size,
                              hipStream_t stream) {
    const float* feat = (const float*)d_in[0];  // [8,1024,64]
    const float* geom = (const float*)d_in[1];  // [8,1024,3]
    const float* W    = (const float*)d_in[2];  // [3,64,64]
    float* out        = (float*)d_out;          // [8,1024,64]

    const int nblocks = BATCHSZ * NPTS / WPB;   // 2048 blocks x 256 threads

    if (ws_size >= (size_t)(3 * COUT * CIN) * sizeof(float)) {
        float* Wt = (float*)d_ws;
        transpose_W_kernel<<<(3 * COUT * CIN + 255) / 256, 256, 0, stream>>>(W, Wt);
        neigh_conv_kernel<true><<<nblocks, WPB * 64, 0, stream>>>(feat, geom, Wt, out);
    } else {
        neigh_conv_kernel<false><<<nblocks, WPB * 64, 0, stream>>>(feat, geom, W, out);
    }
}

// Round 3
// 28.815 us; speedup vs baseline: 1.9069x; 1.0110x over previous
//
#include <hip/hip_runtime.h>

// NeighborsConvolution: out[z,a,i] = sum_{b,x,j} [|r_b-r_a|<0.5] * (r_b-r_a)_x * W[x,i,j] * feat[z,b,j]
// B=8, N=1024, CIN=COUT=64.
//
// R3 changes vs R2 (epilogue W-traffic-bound: 8192 waves x 48KB = 400MB L2):
//  - Single fused kernel (no transpose launch). W transposed into LDS once per
//    block ([g][i][e], g=xj/4, e=xj%4 -> b128-friendly, conflict-free reads).
//  - 512-thread blocks, 8 points each; LDS = W 48KB + geo 12KB + tmp 6KB
//    (+16KB reduce buffer aliased over geo) = 70KB -> 2 blocks/CU.
//  - xj-split epilogue: wave w holds W groups [6w,6w+6) in registers, computes
//    partials for ALL 8 points, cross-wave LDS reduce. W read once per BLOCK.

#define BATCHSZ 8
#define NPTS 1024
#define CIN 64
#define COUT 64
#define NXJ (3 * CIN)       // 192
#define NG (NXJ / 4)        // 48 float4-groups
#define PPB 8               // points (waves) per block
#define BS (PPB * 64)       // 512 threads

__global__ __launch_bounds__(BS, 4) void neigh_conv_kernel(
    const float* __restrict__ feat,  // [B,N,CIN]
    const float* __restrict__ geom,  // [B,N,3]
    const float* __restrict__ W,     // [3,COUT,CIN]
    float* __restrict__ out)         // [B,N,COUT]
{
    const int lane = threadIdx.x & 63;
    const int wv   = threadIdx.x >> 6;
    const int p    = blockIdx.x * PPB + wv;   // this wave's point
    const int a    = p & (NPTS - 1);
    const int z    = p >> 10;                 // uniform across block (8 | 1024)

    __shared__ __align__(16) float Wl[NG * COUT * 4];   // 48 KB  [g][i][e]
    __shared__ __align__(16) float geoRed[PPB * PPB * COUT]; // 16 KB: geo (12KB) then red[8][8][64]
    __shared__ __align__(16) float tmp[PPB][NXJ];       // 6 KB

    // ---- Stage geometry (coalesced float4) ----
    {
        const float4* src = (const float4*)(geom + (size_t)z * NPTS * 3);
        float4* dst = (float4*)geoRed;
        #pragma unroll
        for (int k = threadIdx.x; k < NPTS * 3 / 4; k += BS)
            dst[k] = src[k];
    }
    // ---- Stage W transposed: element (x,i,j) -> Wl[(x*64+j)/4][i][(x*64+j)%4] ----
    {
        const float4* w4 = (const float4*)W;     // 4 consecutive j, same (x,i)
        float4* wl4 = (float4*)Wl;
        #pragma unroll
        for (int k = threadIdx.x; k < 3 * COUT * CIN / 4; k += BS) {
            const int x  = k >> 10;              // k*4 / 4096
            const int i  = (k >> 4) & 63;        // (k*4 / 64) % 64
            const int j0 = (k << 2) & 63;        // 4-aligned
            const int g  = (x * CIN + j0) >> 2;  // all 4 elems share g
            wl4[g * COUT + i] = w4[k];
        }
    }
    __syncthreads();

    const float* geo = geoRed;
    const float gax = geo[a * 3 + 0];
    const float gay = geo[a * 3 + 1];
    const float gaz = geo[a * 3 + 2];
    const float* fz = feat + (size_t)z * NPTS * CIN;

    float acc0 = 0.f, acc1 = 0.f, acc2 = 0.f;

    for (int bb = 0; bb < NPTS; bb += 64) {
        const int b = bb + lane;
        float dx, dy, dz, d2;
        {
            // Bit-exact vs numpy near the boundary: no fma contraction,
            // left-assoc adds. norm<0.5 <=> d2<0.25 exactly.
            #pragma clang fp contract(off)
            dx = geo[b * 3 + 0] - gax;
            dy = geo[b * 3 + 1] - gay;
            dz = geo[b * 3 + 2] - gaz;
            d2 = dx * dx + dy * dy + dz * dz;
        }
        unsigned long long m = __ballot(d2 < 0.25f);
        // wave-uniform mask; ~4-5 neighbors total expected over all 16 iters
        while (m) {
            const int src = __ffsll((unsigned long long)m) - 1;
            m &= (m - 1);
            const float ddx = __shfl(dx, src);
            const float ddy = __shfl(dy, src);
            const float ddz = __shfl(dz, src);
            const float f = fz[(size_t)(bb + src) * CIN + lane];  // coalesced 256B
            acc0 = fmaf(ddx, f, acc0);
            acc1 = fmaf(ddy, f, acc1);
            acc2 = fmaf(ddz, f, acc2);
        }
    }

    tmp[wv][0 * CIN + lane] = acc0;
    tmp[wv][1 * CIN + lane] = acc1;
    tmp[wv][2 * CIN + lane] = acc2;
    __syncthreads();   // after this, geo region is dead -> reuse as red[8][8][64]

    // ---- Epilogue: wave wv owns W groups [6wv, 6wv+6), all 8 points ----
    float* red = geoRed;   // red[w][p][i] = w*512 + p*64 + i
    {
        const int g0 = wv * (NG / PPB);          // 6 groups
        const float4* wl4 = (const float4*)Wl;
        float4 wr[NG / PPB];
        #pragma unroll
        for (int q = 0; q < NG / PPB; ++q)
            wr[q] = wl4[(g0 + q) * COUT + lane]; // conflict-free b128

        #pragma unroll
        for (int pp = 0; pp < PPB; ++pp) {
            const float4* t4 = (const float4*)tmp[pp];
            float acc = 0.f;
            #pragma unroll
            for (int q = 0; q < NG / PPB; ++q) {
                const float4 t = t4[g0 + q];     // uniform -> LDS broadcast
                acc = fmaf(t.x, wr[q].x, acc);
                acc = fmaf(t.y, wr[q].y, acc);
                acc = fmaf(t.z, wr[q].z, acc);
                acc = fmaf(t.w, wr[q].w, acc);
            }
            red[(wv * PPB + pp) * COUT + lane] = acc;
        }
    }
    __syncthreads();

    // ---- Cross-wave reduce: thread (wv=point, lane=channel) ----
    float o = 0.f;
    #pragma unroll
    for (int w = 0; w < PPB; ++w)
        o += red[(w * PPB + wv) * COUT + lane];  // conflict-free, stride 2KB

    out[(size_t)p * COUT + lane] = o;
}

extern "C" void kernel_launch(void* const* d_in, const int* in_sizes, int n_in,
                              void* d_out, int out_size, void* d_ws, size_t ws_size,
                              hipStream_t stream) {
    const float* feat = (const float*)d_in[0];  // [8,1024,64]
    const float* geom = (const float*)d_in[1];  // [8,1024,3]
    const float* W    = (const float*)d_in[2];  // [3,64,64]
    float* out        = (float*)d_out;          // [8,1024,64]

    const int nblocks = BATCHSZ * NPTS / PPB;   // 1024 blocks x 512 threads
    neigh_conv_kernel<<<nblocks, BS, 0, stream>>>(feat, geom, W, out);
}

// Round 4
// 21.080 us; speedup vs baseline: 2.6066x; 1.3669x over previous
//
#include <hip/hip_runtime.h>

// NeighborsConvolution: out[z,a,i] = sum_{b,x,j} [|r_b-r_a|<0.5] * (r_b-r_a)_x * W[x,i,j] * feat[z,b,j]
// B=8, N=1024, CIN=COUT=64.
//
// R4 vs R3 (scan-latency-bound + 2 block-generations):
//  - Gather-then-process scan: ballot steps compact (b,dx,dy,dz) into a
//    per-wave LDS list (no inner while -> 16 steps pipeline); neighbors then
//    processed 4-at-a-time with independent feat loads (batched vmcnt).
//  - W via global transposed Wt (coalesced 1KB/instr, 6 loads/wave).
//  - LDS 34KB (geo 12K + list/red aliased 16K + tmp 6K) -> 4 blocks/CU,
//    32 waves/CU, ONE generation. __launch_bounds__(512,8) caps VGPR at 64.

#define BATCHSZ 8
#define NPTS 1024
#define CIN 64
#define COUT 64
#define NXJ (3 * CIN)   // 192
#define NG (NXJ / 4)    // 48 float4 groups
#define PPB 8           // points (waves) per block
#define BS (PPB * 64)   // 512
#define CAP 128         // per-wave neighbor list capacity
#define GPW (NG / PPB)  // 6 W-groups per wave in epilogue

// smem layout (floats):
//  [0,3072)     geo (12KB)
//  [3072,7168)  list during scan / red during epilogue (16KB)
//               per-wave list base 3072+wv*512: [0,128) b, [128,256) dx,
//               [256,384) dy, [384,512) dz
//  [7168,8704)  tmp[8][192] (6KB)
#define SM_LR 3072
#define SM_TMP 7168
#define SM_TOTAL 8704

__global__ __launch_bounds__(256) void transpose_W_kernel(
    const float* __restrict__ W,   // [3][COUT][CIN]
    float* __restrict__ Wt)        // [NG][COUT][4]
{
    const int t = blockIdx.x * 256 + threadIdx.x;
    if (t >= 3 * COUT * CIN) return;
    const int x = t >> 12;
    const int i = (t >> 6) & 63;
    const int j = t & 63;
    const int xj = x * CIN + j;
    Wt[((xj >> 2) * COUT + i) * 4 + (xj & 3)] = W[t];
}

template <bool WT>
__global__ __launch_bounds__(BS, 8) void neigh_conv_kernel(
    const float* __restrict__ feat,  // [B,N,CIN]
    const float* __restrict__ geom,  // [B,N,3]
    const float* __restrict__ Wv,    // WT ? Wt[NG][64][4] : W[3][64][64]
    float* __restrict__ out)         // [B,N,COUT]
{
    const int lane = threadIdx.x & 63;
    const int wv   = threadIdx.x >> 6;
    const int p    = blockIdx.x * PPB + wv;
    const int a    = p & (NPTS - 1);
    const int z    = p >> 10;        // uniform across block (8 | 1024)

    __shared__ __align__(16) float smem[SM_TOTAL];

    // ---- stage geometry (coalesced float4) ----
    {
        const float4* src = (const float4*)(geom + (size_t)z * NPTS * 3);
        float4* dst = (float4*)smem;
        for (int k = threadIdx.x; k < NPTS * 3 / 4; k += BS)
            dst[k] = src[k];
    }
    __syncthreads();

    const float* geo = smem;
    const float gax = geo[a * 3 + 0];
    const float gay = geo[a * 3 + 1];
    const float gaz = geo[a * 3 + 2];
    const float* fz = feat + (size_t)z * NPTS * CIN;

    int*   lb = (int*)(smem + SM_LR) + wv * 512;
    float* lx = smem + SM_LR + wv * 512 + 128;
    float* ly = lx + 128;
    float* lz = ly + 128;

    const unsigned long long ltmask = (1ull << lane) - 1ull;
    float acc0 = 0.f, acc1 = 0.f, acc2 = 0.f;
    int nn = 0;

    // ---- scan: ballot + compact (no data-dependent inner loop) ----
    #pragma unroll 4
    for (int bb = 0; bb < NPTS; bb += 64) {
        const int b = bb + lane;
        float dx, dy, dz, d2;
        {
            // Bit-exact vs numpy near the boundary: no fma contraction,
            // left-assoc adds. norm<0.5 <=> d2<0.25 exactly.
            #pragma clang fp contract(off)
            dx = geo[b * 3 + 0] - gax;
            dy = geo[b * 3 + 1] - gay;
            dz = geo[b * 3 + 2] - gaz;
            d2 = dx * dx + dy * dy + dz * dz;
        }
        const bool hit = d2 < 0.25f;
        const unsigned long long m = __ballot(hit);
        const int c = __popcll(m);
        if (nn + c <= CAP) {               // wave-uniform
            if (hit) {
                const int s = nn + __popcll(m & ltmask);
                lb[s] = b; lx[s] = dx; ly[s] = dy; lz[s] = dz;
            }
            nn += c;
        } else {
            // overflow fallback (statistically never for this data)
            unsigned long long mm = m;
            while (mm) {
                const int src = __ffsll(mm) - 1;
                mm &= mm - 1ull;
                const float ddx = __shfl(dx, src);
                const float ddy = __shfl(dy, src);
                const float ddz = __shfl(dz, src);
                const float f = fz[(size_t)(bb + src) * CIN + lane];
                acc0 = fmaf(ddx, f, acc0);
                acc1 = fmaf(ddy, f, acc1);
                acc2 = fmaf(ddz, f, acc2);
            }
        }
    }

    // pad to multiple of 4 with null records (b=a -> diff 0, contributes 0)
    {
        const int npad = (4 - (nn & 3)) & 3;
        if (lane < npad) {
            lb[nn + lane] = a;
            lx[nn + lane] = 0.f; ly[nn + lane] = 0.f; lz[nn + lane] = 0.f;
        }
        nn += npad;
    }

    // ---- process neighbors 4 at a time: independent feat loads ----
    for (int k = 0; k < nn; k += 4) {
        const int b0 = lb[k + 0], b1 = lb[k + 1], b2 = lb[k + 2], b3 = lb[k + 3];
        const float f0 = fz[(size_t)b0 * CIN + lane];
        const float f1 = fz[(size_t)b1 * CIN + lane];
        const float f2 = fz[(size_t)b2 * CIN + lane];
        const float f3 = fz[(size_t)b3 * CIN + lane];
        const float x0 = lx[k + 0], y0 = ly[k + 0], z0 = lz[k + 0];
        const float x1 = lx[k + 1], y1 = ly[k + 1], z1 = lz[k + 1];
        const float x2 = lx[k + 2], y2 = ly[k + 2], z2 = lz[k + 2];
        const float x3 = lx[k + 3], y3 = ly[k + 3], z3 = lz[k + 3];
        acc0 = fmaf(x0, f0, acc0); acc1 = fmaf(y0, f0, acc1); acc2 = fmaf(z0, f0, acc2);
        acc0 = fmaf(x1, f1, acc0); acc1 = fmaf(y1, f1, acc1); acc2 = fmaf(z1, f1, acc2);
        acc0 = fmaf(x2, f2, acc0); acc1 = fmaf(y2, f2, acc1); acc2 = fmaf(z2, f2, acc2);
        acc0 = fmaf(x3, f3, acc0); acc1 = fmaf(y3, f3, acc1); acc2 = fmaf(z3, f3, acc2);
    }

    float* tmp = smem + SM_TMP + wv * NXJ;
    tmp[0 * CIN + lane] = acc0;
    tmp[1 * CIN + lane] = acc1;
    tmp[2 * CIN + lane] = acc2;
    __syncthreads();   // list region dead after this -> reuse as red

    // ---- epilogue: wave wv owns W groups [6wv,6wv+6), all 8 points ----
    const int g0 = wv * GPW;
    float4 wr[GPW];
    if (WT) {
        const float4* w4 = (const float4*)Wv;
        #pragma unroll
        for (int q = 0; q < GPW; ++q)
            wr[q] = w4[(g0 + q) * COUT + lane];   // coalesced 1KB/instr
    } else {
        #pragma unroll
        for (int q = 0; q < GPW; ++q) {
            const int xj = 4 * (g0 + q);
            wr[q].x = Wv[((xj + 0) >> 6) * 4096 + lane * 64 + ((xj + 0) & 63)];
            wr[q].y = Wv[((xj + 1) >> 6) * 4096 + lane * 64 + ((xj + 1) & 63)];
            wr[q].z = Wv[((xj + 2) >> 6) * 4096 + lane * 64 + ((xj + 2) & 63)];
            wr[q].w = Wv[((xj + 3) >> 6) * 4096 + lane * 64 + ((xj + 3) & 63)];
        }
    }

    float* red = smem + SM_LR;   // red[w*8+pp][i]
    #pragma unroll
    for (int pp = 0; pp < PPB; ++pp) {
        const float4* t4 = (const float4*)(smem + SM_TMP + pp * NXJ);
        float acc = 0.f;
        #pragma unroll
        for (int q = 0; q < GPW; ++q) {
            const float4 t = t4[g0 + q];          // uniform -> LDS broadcast
            acc = fmaf(t.x, wr[q].x, acc);
            acc = fmaf(t.y, wr[q].y, acc);
            acc = fmaf(t.z, wr[q].z, acc);
            acc = fmaf(t.w, wr[q].w, acc);
        }
        red[(wv * PPB + pp) * COUT + lane] = acc;
    }
    __syncthreads();

    float o = 0.f;
    #pragma unroll
    for (int w = 0; w < PPB; ++w)
        o += red[(w * PPB + wv) * COUT + lane];   // conflict-free

    out[(size_t)p * COUT + lane] = o;
}

extern "C" void kernel_launch(void* const* d_in, const int* in_sizes, int n_in,
                              void* d_out, int out_size, void* d_ws, size_t ws_size,
                              hipStream_t stream) {
    const float* feat = (const float*)d_in[0];  // [8,1024,64]
    const float* geom = (const float*)d_in[1];  // [8,1024,3]
    const float* W    = (const float*)d_in[2];  // [3,64,64]
    float* out        = (float*)d_out;          // [8,1024,64]

    const int nblocks = BATCHSZ * NPTS / PPB;   // 1024 blocks x 512 threads

    if (ws_size >= (size_t)(3 * COUT * CIN) * sizeof(float)) {
        float* Wt = (float*)d_ws;
        transpose_W_kernel<<<(3 * COUT * CIN + 255) / 256, 256, 0, stream>>>(W, Wt);
        neigh_conv_kernel<true><<<nblocks, BS, 0, stream>>>(feat, geom, Wt, out);
    } else {
        neigh_conv_kernel<false><<<nblocks, BS, 0, stream>>>(feat, geom, W, out);
    }
}